// Round 26
// baseline (156.970 us; speedup 1.0000x reference)
//
#include <hip/hip_runtime.h>
#include <math.h>

#define NB 8
#define IN_CH 2
#define OUT_CHN 4
#define NSINC 4
#define CONDC 32
#define KK 256
#define HOP 64
#define TT 65536
#define NF 1025
#define LL (HOP*(NF-1)+KK)   /* 65792 */
#define PI_F 3.14159265358979323846f

/* ws layout (floats):
   wtab    @ 0       : 98304
   par     @ 98304   : 524800
   X       @ 623104  : 4198400
   acc     @ 4821504 : 2105344
   h_part  @ 6926848 : 1049600
   g2      @ 8042240 : 65536 (u32 packed bf16 pairs)
   wfh     @ 8107776 : 131072 ushort
   total 8,238,848 floats = 33 MB */
#define WTAB_OFF 0
#define PAR_OFF  98304
#define X_OFF    623104
#define ACC_OFF  4821504
#define ACC_N    2105344
#define HPART_OFF 6926848
#define G2_OFF   8042240
#define WFH_OFF  8107776

#define FPAD 264

typedef __attribute__((ext_vector_type(8))) short bf16x8;
typedef __attribute__((ext_vector_type(4))) float f32x4;

__device__ __forceinline__ unsigned short tobf16_rn(float v) {
    unsigned b = __float_as_uint(v);
    return (unsigned short)((b + 0x7FFFu + ((b >> 16) & 1u)) >> 16);
}

__device__ __forceinline__ float frombf16(unsigned short u) {
    return __uint_as_float(((unsigned)u) << 16);
}

/* sinc(x)=sin(pi x)/(pi x) via Taylor in (pi x)^2; |pi x| <= 1.571 here -> err < 4e-8 */
__device__ __forceinline__ float sincpoly(float x) {
    float y = PI_F * x;
    float y2 = y * y;
    return 1.f + y2 * (-1.6666667e-1f + y2 * (8.3333333e-3f + y2 * (-1.9841270e-4f
              + y2 * (2.7557319e-6f + y2 * (-2.5052108e-8f)))));
}

/* ---- MERGED setup: [0,768) wtab; [768,1792) w1 hi-plane split; [1792,2049) gsetup->g2 ---- */
__global__ __launch_bounds__(256) void k_setup(unsigned short* __restrict__ wtab,
                                               const float* __restrict__ w1,
                                               unsigned short* __restrict__ wfh,
                                               unsigned short* __restrict__ g2u) {
    const int blk = blockIdx.x;
    const int t = threadIdx.x;
    if (blk < 768) {
        int idx = blk * 256 + t;
        int m = idx >> 16;
        int rem = idx & 65535;
        int oc = rem >> 8;
        int kd = rem & 255;
        const float ang = 2.f * PI_F / 256.f;
        float v;
        if (m < 2) {
            if (oc == 0) v = 1.f;
            else if (oc == 1) v = (kd & 1) ? -1.f : 1.f;
            else {
                int nu = oc >> 1;
                float th = ang * (float)((nu * kd) & 255);
                v = (oc & 1) ? -sinf(th) : cosf(th);
            }
            if (m == 0) v *= 0.5f * (1.f - cosf(ang * (float)kd));
        } else {
            float s;
            if (kd == 0) s = 1.f;
            else if (kd == 1) s = (oc & 1) ? -1.f : 1.f;
            else {
                int nu = kd >> 1;
                float th = ang * (float)((nu * oc) & 255);
                s = (kd & 1) ? -2.f * sinf(th) : 2.f * cosf(th);
            }
            v = s * (1.f / 256.f) * 0.5f * (1.f - cosf(ang * (float)oc));
        }
        int nt = oc >> 4, sel = oc & 15;
        int ks = kd >> 5, koct = (kd >> 3) & 3, e = kd & 7;
        wtab[(m << 16) | (nt << 12) | (ks << 9) | (koct << 7) | (sel << 3) | e] = tobf16_rn(v);
    } else if (blk < 1792) {
        int idx = (blk - 768) * 256 + t;
        int c = idx >> 13;
        int cin = (idx >> 8) & 31;
        int k = idx & 255;
        int cin2 = cin * 2 + (c >> 4);
        int frag = ((k >> 5) << 9) | (((k >> 3) & 3) << 7) | ((c & 15) << 3) | (k & 7);
        wfh[(cin2 << 12) | frag] = tobf16_rn(w1[idx]);
    } else {
        const int wi = blk - 1792;      /* 0..256 */
        const float ang = 2.f * PI_F / 256.f;
        const float w = (float)wi * (1.f / 128.f) - 1.f;
        const int col = t;
        const int nu = col >> 1;
        const float phi = ang * (float)nu;
        const float cphi = cosf(phi), sphi = sinf(phi);
        const float cang = cosf(ang), sang = sinf(ang);
        float c = 1.f, s = 0.f;
        float ca = 1.f, sa = 0.f;
        float sum = 0.f;
        for (int k = 0; k < 256; ++k) {
            float x = w * ((float)k - 128.f) * (1.f / 256.f) + 1e-6f;
            float sp = sincpoly(x);
            float fsc = (0.42f - 0.5f * ca + 0.08f * (2.f * ca * ca - 1.f)) * (1.f / 1024.f);
            float coef;
            if (col == 0) coef = 1.f;
            else if (col == 1) coef = (k & 1) ? -1.f : 1.f;
            else coef = (col & 1) ? -s : c;
            sum += sp * fsc * coef;
            float cn = c * cphi - s * sphi;
            s = s * cphi + c * sphi;
            c = cn;
            float can = ca * cang - sa * sang;
            sa = sa * cang + ca * sang;
            ca = can;
        }
        unsigned short v16 = tobf16_rn(sum);
        if (wi < 256) g2u[2 * ((wi << 8) + col)] = v16;
        if (wi >= 1)  g2u[2 * (((wi - 1) << 8) + col) + 1] = v16;
    }
}

/* ---- MERGED heavy (verified R25): [0,544) hconv bf16xbf16; [544,1072) frames DFT ---- */
__global__ __launch_bounds__(256) void k_heavy(const float* __restrict__ cond,
                                               const unsigned short* __restrict__ wfh,
                                               float* __restrict__ h_part,
                                               const float* __restrict__ x,
                                               const unsigned short* __restrict__ wtab,
                                               float* __restrict__ X) {
    __shared__ __align__(16) unsigned short s_a[4840];
    const int blk = blockIdx.x;
    const int t = threadIdx.x;
    const int w = t >> 6;
    const int l = t & 63;
    const int sel16 = l & 15;
    const int koct = l >> 4;

    if (blk < 544) {
        const int ftile = blk % 17;
        const int g = (blk / 17) & 3;
        const int b = blk / 68;
        const int f0 = ftile * 64;
        const long pos0 = (long)f0 * HOP - 128;

        const unsigned short* WH = wfh + (l << 3);

        f32x4 acc0 = {0.f, 0.f, 0.f, 0.f};
        f32x4 acc1 = {0.f, 0.f, 0.f, 0.f};

        for (int ci = 0; ci < 8; ++ci) {
            const int cin = g * 8 + ci;
            __syncthreads();
            const float* crow = &cond[((long)b * CONDC + cin) * TT];
            for (int u = t; u < 4288; u += 256) {
                long p = pos0 + u;
                if (p < 0) p = -p;
                if (p >= TT) p = 2 * (TT - 1) - p;
                int off = u + ((u >> 6) << 3);
                s_a[off] = tobf16_rn(crow[p]);
            }
            __syncthreads();
            const int flocal = w * 16 + sel16;
            const int c20 = (cin * 2) << 12;
            const int c21 = (cin * 2 + 1) << 12;
            #pragma unroll
            for (int ks = 0; ks < 8; ++ks) {
                int u = flocal * 64 + ks * 32 + koct * 8;
                int aoff = u + ((u >> 6) << 3);
                bf16x8 ahi = *(const bf16x8*)&s_a[aoff];
                bf16x8 b0h = *(const bf16x8*)&WH[c20 + (ks << 9)];
                bf16x8 b1h = *(const bf16x8*)&WH[c21 + (ks << 9)];
                acc0 = __builtin_amdgcn_mfma_f32_16x16x32_bf16(ahi, b0h, acc0, 0, 0, 0);
                acc1 = __builtin_amdgcn_mfma_f32_16x16x32_bf16(ahi, b1h, acc1, 0, 0, 0);
            }
        }

        #pragma unroll
        for (int j = 0; j < 4; ++j) {
            int f = f0 + w * 16 + koct * 4 + j;
            if (f < NF) {
                long base = (((long)g * NB + b) * NF + f) * CONDC;
                h_part[base + sel16] = acc0[j];
                h_part[base + 16 + sel16] = acc1[j];
            }
        }
    } else {
        const int u2 = blk - 544;
        const int ftile = u2 % 33;
        const int bi = u2 / 33;
        const int f0 = ftile * 32;
        const long pos0 = (long)f0 * HOP - 128;
        const int rh = w & 1;
        const int nh = w >> 1;
        const int flocal = rh * 16 + sel16;

        const float* xrow = &x[(long)bi * TT];
        for (int u = t; u < 2240; u += 256) {
            long p = pos0 + u;
            if (p < 0) p = -p;
            if (p >= TT) p = 2 * (TT - 1) - p;
            int off = u + ((u >> 6) << 3);
            s_a[off] = tobf16_rn(xrow[p]);
        }
        __syncthreads();

        const unsigned short* WF = wtab + (l << 3);
        for (int s = 0; s < 8; ++s) {
            const int nt = nh * 8 + s;
            f32x4 acc = {0.f, 0.f, 0.f, 0.f};
            #pragma unroll
            for (int ks = 0; ks < 8; ++ks) {
                int u = flocal * 64 + ks * 32 + koct * 8;
                int aoff = u + ((u >> 6) << 3);
                bf16x8 ah = *(const bf16x8*)&s_a[aoff];
                bf16x8 bh = *(const bf16x8*)&WF[(nt << 12) + (ks << 9)];
                acc = __builtin_amdgcn_mfma_f32_16x16x32_bf16(ah, bh, acc, 0, 0, 0);
            }
            #pragma unroll
            for (int j = 0; j < 4; ++j) {
                int f = f0 + rh * 16 + koct * 4 + j;
                if (f < NF) X[((long)bi * NF + f) * 256 + nt * 16 + sel16] = acc[j];
            }
        }
    }
}

/* ---- params (+ acc zeroing) ---- */
__global__ __launch_bounds__(64) void k_params(const float* __restrict__ h_part,
                                               const float* __restrict__ w2,
                                               const float* __restrict__ b1,
                                               const float* __restrict__ b2,
                                               float* __restrict__ par,
                                               float* __restrict__ accz) {
    __shared__ float s_h[CONDC];
    const int f = blockIdx.x;
    const int b = blockIdx.y;
    const int t = threadIdx.x;
    {
        int gid = (b * NF + f) * 64 + t;
        for (int u = gid; u < ACC_N; u += NF * NB * 64) accz[u] = 0.f;
    }
    if (t < CONDC) {
        float v = b1[t];
        #pragma unroll
        for (int g = 0; g < 4; ++g)
            v += h_part[(((long)g * NB + b) * NF + f) * CONDC + t];
        s_h[t] = (v >= 0.f) ? v : 0.01f * v;
    }
    __syncthreads();
    float acc = b2[t];
    #pragma unroll 8
    for (int cin = 0; cin < CONDC; ++cin) acc += s_h[cin] * w2[t * CONDC + cin];
    par[((long)b * NF + f) * 64 + t] = tanhf(acc);
}

/* ---- FUSED: R25 epilogue + BATCHED per-row loads; launch_bounds(256,2) relaxes
   the VGPR budget so the 8 g2 + 2 X loads can stay in flight. ---- */
__global__ __launch_bounds__(256, 2) void k_fused(const float* __restrict__ par,
                                                  const unsigned* __restrict__ g2,
                                                  const unsigned short* __restrict__ wtab,
                                                  const float* __restrict__ X,
                                                  float* __restrict__ accb,
                                                  const float* __restrict__ bias,
                                                  float* __restrict__ out) {
    __shared__ __align__(16) unsigned short s_y[16 * FPAD];   /* 8.4 KB */
    __shared__ float s_ola[1216];                              /* 4.9 KB */
    __shared__ float s_parl[256];                              /* 1 KB */

    const int idx = blockIdx.x;     /* 0..2079 */
    const int o = idx / 520;
    const int rem = idx - o * 520;
    const int ftile = rem >> 3;     /* 0..64 */
    const int b = rem & 7;
    const int bo = b * 4 + o;
    const int t = threadIdx.x;
    const int f0 = ftile * 16;
    const int w = t >> 6;           /* 0..3 */
    const int l = t & 63;
    const int sel16 = l & 15;
    const int koct = l >> 4;

    const unsigned short* WI = wtab + 2 * 65536 + (l << 3);
    const float biaso = bias[o];

    {
        int f_r = t >> 4;
        int idx2 = t & 15;
        int isel = idx2 >> 3;
        int q = idx2 & 7;
        int col = (o * 2 + isel) * 4 + (q & 3) + ((q >> 2) * 32);
        int fc = f0 + f_r;
        if (fc >= NF) fc = NF - 1;
        s_parl[t] = par[((long)b * NF + fc) * 64 + col];
    }
    __syncthreads();

    /* phase 1: batched-load H lerp + 1-shfl cmul -> s_y */
    #pragma unroll 1
    for (int r = 0; r < 16; ++r) {
        int f = f0 + r;
        bool valid = (f < NF);
        float av[8], fr[8];
        int gi[8];
        #pragma unroll
        for (int q = 0; q < 8; ++q) {
            int iq = q >> 2, s4 = q & 3;
            av[q] = s_parl[r * 16 + iq * 8 + s4];
            float wv = s_parl[r * 16 + iq * 8 + 4 + s4];
            float u = (wv + 1.f) * 128.f;
            int gg = (int)floorf(u);
            gg = (gg < 0) ? 0 : (gg > 255 ? 255 : gg);
            fr[q] = u - (float)gg;
            gi[q] = gg;
        }
        unsigned pk[8];
        #pragma unroll
        for (int q = 0; q < 8; ++q) pk[q] = g2[(gi[q] << 8) + t];
        float2 xp0 = make_float2(0.f, 0.f), xp1 = make_float2(0.f, 0.f);
        if (valid) {
            xp0 = *(const float2*)&X[((long)(b * 2 + 0) * NF + f) * 256 + (t & ~1)];
            xp1 = *(const float2*)&X[((long)(b * 2 + 1) * NF + f) * 256 + (t & ~1)];
        }
        float H0 = 0.f, H1 = 0.f;
        #pragma unroll
        for (int q = 0; q < 8; ++q) {
            float glo = frombf16((unsigned short)(pk[q] & 0xffffu));
            float ghi = frombf16((unsigned short)(pk[q] >> 16));
            float Hq = av[q] * (glo + fr[q] * (ghi - glo));
            if (q < 4) H0 += Hq; else H1 += Hq;
        }
        float Hx0 = __shfl_xor(H0, 1);
        float Hx1 = __shfl_xor(H1, 1);
        float yv;
        if (t < 2) {
            yv = H0 * ((t & 1) ? xp0.y : xp0.x) + H1 * ((t & 1) ? xp1.y : xp1.x);
        } else if (t & 1) {
            yv = (H0 * xp0.x + Hx0 * xp0.y) + (H1 * xp1.x + Hx1 * xp1.y);
        } else {
            yv = (H0 * xp0.x - Hx0 * xp0.y) + (H1 * xp1.x - Hx1 * xp1.y);
        }
        s_y[r * FPAD + t] = tobf16_rn(yv);
    }

    /* phase 2: 16-row inverse DFT from s_y, OLA in LDS (verified R18) */
    __syncthreads();
    for (int u = t; u < 1216; u += 256) s_ola[u] = 0.f;
    __syncthreads();
    for (int s = 0; s < 4; ++s) {
        const int nt = w * 4 + s;
        f32x4 acc = {0.f, 0.f, 0.f, 0.f};
        #pragma unroll
        for (int ks = 0; ks < 8; ++ks) {
            bf16x8 ah = *(const bf16x8*)&s_y[sel16 * FPAD + ks * 32 + koct * 8];
            bf16x8 bh = *(const bf16x8*)&WI[(nt << 12) + (ks << 9)];
            acc = __builtin_amdgcn_mfma_f32_16x16x32_bf16(ah, bh, acc, 0, 0, 0);
        }
        #pragma unroll
        for (int j = 0; j < 4; ++j) {
            int row = koct * 4 + j;
            int n = nt * 16 + sel16;
            atomicAdd(&s_ola[row * 64 + n], acc[j]);
        }
    }
    __syncthreads();
    /* epilogue (verified R25): edges -> atomic acc; interior pos<65536 -> out directly */
    for (int u = t; u < 1216; u += 256) {
        long pos = (long)f0 * HOP + u;
        if (pos >= (long)LL) continue;
        float v = s_ola[u];
        if (u < 192 || u >= 1024) {
            atomicAdd(&accb[(long)bo * LL + pos], v);
        } else if (pos < 65536) {
            out[(long)bo * TT + (pos - 128)] = v * (1.f / 1.5f) + biaso;
        }
    }
}

/* ---- norm: boundary/overlap samples only (verified R25) ---- */
__global__ __launch_bounds__(256) void k_norm(const float* __restrict__ accbuf,
                                              const float* __restrict__ bias,
                                              float* __restrict__ out) {
    int idx = blockIdx.x * 256 + threadIdx.x;
    if (idx >= NB * OUT_CHN * TT) return;
    int tpos = idx & (TT - 1);
    int bo = idx >> 16;
    int o = bo & 3;
    int tt = tpos + 128;
    if (tt >= 192 && tt < 65536 && (tt & 1023) >= 192) return;
    float env;
    if (tt >= 192 && tt < (NF - 1) * HOP) {
        env = 1.5f;
    } else {
        env = 0.f;
        int fhi = tt >> 6;
        #pragma unroll
        for (int d = 0; d < 4; ++d) {
            int f = fhi - d;
            int n = tt - f * HOP;
            if (f >= 0 && f < NF && n >= 0 && n < KK) {
                float angn = (2.f * PI_F / 256.f) * (float)n;
                float wv = 0.5f * (1.f - cosf(angn));
                env += wv * wv;
            }
        }
    }
    out[idx] = accbuf[(long)bo * LL + tt] / env + bias[o];
}

extern "C" void kernel_launch(void* const* d_in, const int* in_sizes, int n_in,
                              void* d_out, int out_size, void* d_ws, size_t ws_size,
                              hipStream_t stream) {
    const float* x    = (const float*)d_in[0];
    const float* cond = (const float*)d_in[1];
    const float* w1   = (const float*)d_in[2];
    const float* b1   = (const float*)d_in[3];
    const float* w2   = (const float*)d_in[4];
    const float* b2   = (const float*)d_in[5];
    const float* bias = (const float*)d_in[6];
    float* out = (float*)d_out;
    float* ws  = (float*)d_ws;
    unsigned short* wtab = (unsigned short*)(ws + WTAB_OFF);
    float* par    = ws + PAR_OFF;
    float* X      = ws + X_OFF;
    float* acc    = ws + ACC_OFF;
    float* h_part = ws + HPART_OFF;
    unsigned* g2  = (unsigned*)(ws + G2_OFF);
    unsigned short* wfh = (unsigned short*)(ws + WFH_OFF);

    hipLaunchKernelGGL(k_setup, dim3(2049), dim3(256), 0, stream,
                       wtab, w1, wfh, (unsigned short*)g2);
    hipLaunchKernelGGL(k_heavy, dim3(1072), dim3(256), 0, stream,
                       cond, wfh, h_part, x, wtab, X);
    hipLaunchKernelGGL(k_params, dim3(NF, NB), dim3(64), 0, stream, h_part, w2, b1, b2, par, acc);
    hipLaunchKernelGGL(k_fused, dim3(2080), dim3(256), 0, stream, par, g2, wtab, X, acc, bias, out);
    hipLaunchKernelGGL(k_norm, dim3(8192), dim3(256), 0, stream, acc, bias, out);
}

// Round 27
// 153.472 us; speedup vs baseline: 1.0228x; 1.0228x over previous
//
#include <hip/hip_runtime.h>
#include <math.h>

#define NB 8
#define IN_CH 2
#define OUT_CHN 4
#define NSINC 4
#define CONDC 32
#define KK 256
#define HOP 64
#define TT 65536
#define NF 1025
#define LL (HOP*(NF-1)+KK)   /* 65792 */
#define PI_F 3.14159265358979323846f

/* ws layout (floats):
   wtab    @ 0       : 98304
   par     @ 98304   : 524800
   X       @ 623104  : 4198400
   acc     @ 4821504 : 2105344
   h_part  @ 6926848 : 1049600
   g2      @ 8042240 : 65536 (u32 packed bf16 pairs)
   wfh     @ 8107776 : 131072 ushort
   total 8,238,848 floats = 33 MB */
#define WTAB_OFF 0
#define PAR_OFF  98304
#define X_OFF    623104
#define ACC_OFF  4821504
#define ACC_N    2105344
#define HPART_OFF 6926848
#define G2_OFF   8042240
#define WFH_OFF  8107776

#define FPAD 264

typedef __attribute__((ext_vector_type(8))) short bf16x8;
typedef __attribute__((ext_vector_type(4))) float f32x4;

__device__ __forceinline__ unsigned short tobf16_rn(float v) {
    unsigned b = __float_as_uint(v);
    return (unsigned short)((b + 0x7FFFu + ((b >> 16) & 1u)) >> 16);
}

__device__ __forceinline__ float frombf16(unsigned short u) {
    return __uint_as_float(((unsigned)u) << 16);
}

/* sinc(x)=sin(pi x)/(pi x) via Taylor in (pi x)^2; |pi x| <= 1.571 here -> err < 4e-8 */
__device__ __forceinline__ float sincpoly(float x) {
    float y = PI_F * x;
    float y2 = y * y;
    return 1.f + y2 * (-1.6666667e-1f + y2 * (8.3333333e-3f + y2 * (-1.9841270e-4f
              + y2 * (2.7557319e-6f + y2 * (-2.5052108e-8f)))));
}

/* ---- MERGED setup: [0,768) wtab; [768,1792) w1 hi-plane split; [1792,2049) gsetup->g2 ---- */
__global__ __launch_bounds__(256) void k_setup(unsigned short* __restrict__ wtab,
                                               const float* __restrict__ w1,
                                               unsigned short* __restrict__ wfh,
                                               unsigned short* __restrict__ g2u) {
    const int blk = blockIdx.x;
    const int t = threadIdx.x;
    if (blk < 768) {
        int idx = blk * 256 + t;
        int m = idx >> 16;
        int rem = idx & 65535;
        int oc = rem >> 8;
        int kd = rem & 255;
        const float ang = 2.f * PI_F / 256.f;
        float v;
        if (m < 2) {
            if (oc == 0) v = 1.f;
            else if (oc == 1) v = (kd & 1) ? -1.f : 1.f;
            else {
                int nu = oc >> 1;
                float th = ang * (float)((nu * kd) & 255);
                v = (oc & 1) ? -sinf(th) : cosf(th);
            }
            if (m == 0) v *= 0.5f * (1.f - cosf(ang * (float)kd));
        } else {
            float s;
            if (kd == 0) s = 1.f;
            else if (kd == 1) s = (oc & 1) ? -1.f : 1.f;
            else {
                int nu = kd >> 1;
                float th = ang * (float)((nu * oc) & 255);
                s = (kd & 1) ? -2.f * sinf(th) : 2.f * cosf(th);
            }
            v = s * (1.f / 256.f) * 0.5f * (1.f - cosf(ang * (float)oc));
        }
        int nt = oc >> 4, sel = oc & 15;
        int ks = kd >> 5, koct = (kd >> 3) & 3, e = kd & 7;
        wtab[(m << 16) | (nt << 12) | (ks << 9) | (koct << 7) | (sel << 3) | e] = tobf16_rn(v);
    } else if (blk < 1792) {
        int idx = (blk - 768) * 256 + t;
        int c = idx >> 13;
        int cin = (idx >> 8) & 31;
        int k = idx & 255;
        int cin2 = cin * 2 + (c >> 4);
        int frag = ((k >> 5) << 9) | (((k >> 3) & 3) << 7) | ((c & 15) << 3) | (k & 7);
        wfh[(cin2 << 12) | frag] = tobf16_rn(w1[idx]);
    } else {
        const int wi = blk - 1792;      /* 0..256 */
        const float ang = 2.f * PI_F / 256.f;
        const float w = (float)wi * (1.f / 128.f) - 1.f;
        const int col = t;
        const int nu = col >> 1;
        const float phi = ang * (float)nu;
        const float cphi = cosf(phi), sphi = sinf(phi);
        const float cang = cosf(ang), sang = sinf(ang);
        float c = 1.f, s = 0.f;
        float ca = 1.f, sa = 0.f;
        float sum = 0.f;
        for (int k = 0; k < 256; ++k) {
            float x = w * ((float)k - 128.f) * (1.f / 256.f) + 1e-6f;
            float sp = sincpoly(x);
            float fsc = (0.42f - 0.5f * ca + 0.08f * (2.f * ca * ca - 1.f)) * (1.f / 1024.f);
            float coef;
            if (col == 0) coef = 1.f;
            else if (col == 1) coef = (k & 1) ? -1.f : 1.f;
            else coef = (col & 1) ? -s : c;
            sum += sp * fsc * coef;
            float cn = c * cphi - s * sphi;
            s = s * cphi + c * sphi;
            c = cn;
            float can = ca * cang - sa * sang;
            sa = sa * cang + ca * sang;
            ca = can;
        }
        unsigned short v16 = tobf16_rn(sum);
        if (wi < 256) g2u[2 * ((wi << 8) + col)] = v16;
        if (wi >= 1)  g2u[2 * (((wi - 1) << 8) + col) + 1] = v16;
    }
}

/* ---- MERGED heavy (verified R25): [0,544) hconv bf16xbf16; [544,1072) frames DFT ---- */
__global__ __launch_bounds__(256) void k_heavy(const float* __restrict__ cond,
                                               const unsigned short* __restrict__ wfh,
                                               float* __restrict__ h_part,
                                               const float* __restrict__ x,
                                               const unsigned short* __restrict__ wtab,
                                               float* __restrict__ X) {
    __shared__ __align__(16) unsigned short s_a[4840];
    const int blk = blockIdx.x;
    const int t = threadIdx.x;
    const int w = t >> 6;
    const int l = t & 63;
    const int sel16 = l & 15;
    const int koct = l >> 4;

    if (blk < 544) {
        const int ftile = blk % 17;
        const int g = (blk / 17) & 3;
        const int b = blk / 68;
        const int f0 = ftile * 64;
        const long pos0 = (long)f0 * HOP - 128;

        const unsigned short* WH = wfh + (l << 3);

        f32x4 acc0 = {0.f, 0.f, 0.f, 0.f};
        f32x4 acc1 = {0.f, 0.f, 0.f, 0.f};

        for (int ci = 0; ci < 8; ++ci) {
            const int cin = g * 8 + ci;
            __syncthreads();
            const float* crow = &cond[((long)b * CONDC + cin) * TT];
            for (int u = t; u < 4288; u += 256) {
                long p = pos0 + u;
                if (p < 0) p = -p;
                if (p >= TT) p = 2 * (TT - 1) - p;
                int off = u + ((u >> 6) << 3);
                s_a[off] = tobf16_rn(crow[p]);
            }
            __syncthreads();
            const int flocal = w * 16 + sel16;
            const int c20 = (cin * 2) << 12;
            const int c21 = (cin * 2 + 1) << 12;
            #pragma unroll
            for (int ks = 0; ks < 8; ++ks) {
                int u = flocal * 64 + ks * 32 + koct * 8;
                int aoff = u + ((u >> 6) << 3);
                bf16x8 ahi = *(const bf16x8*)&s_a[aoff];
                bf16x8 b0h = *(const bf16x8*)&WH[c20 + (ks << 9)];
                bf16x8 b1h = *(const bf16x8*)&WH[c21 + (ks << 9)];
                acc0 = __builtin_amdgcn_mfma_f32_16x16x32_bf16(ahi, b0h, acc0, 0, 0, 0);
                acc1 = __builtin_amdgcn_mfma_f32_16x16x32_bf16(ahi, b1h, acc1, 0, 0, 0);
            }
        }

        #pragma unroll
        for (int j = 0; j < 4; ++j) {
            int f = f0 + w * 16 + koct * 4 + j;
            if (f < NF) {
                long base = (((long)g * NB + b) * NF + f) * CONDC;
                h_part[base + sel16] = acc0[j];
                h_part[base + 16 + sel16] = acc1[j];
            }
        }
    } else {
        const int u2 = blk - 544;
        const int ftile = u2 % 33;
        const int bi = u2 / 33;
        const int f0 = ftile * 32;
        const long pos0 = (long)f0 * HOP - 128;
        const int rh = w & 1;
        const int nh = w >> 1;
        const int flocal = rh * 16 + sel16;

        const float* xrow = &x[(long)bi * TT];
        for (int u = t; u < 2240; u += 256) {
            long p = pos0 + u;
            if (p < 0) p = -p;
            if (p >= TT) p = 2 * (TT - 1) - p;
            int off = u + ((u >> 6) << 3);
            s_a[off] = tobf16_rn(xrow[p]);
        }
        __syncthreads();

        const unsigned short* WF = wtab + (l << 3);
        for (int s = 0; s < 8; ++s) {
            const int nt = nh * 8 + s;
            f32x4 acc = {0.f, 0.f, 0.f, 0.f};
            #pragma unroll
            for (int ks = 0; ks < 8; ++ks) {
                int u = flocal * 64 + ks * 32 + koct * 8;
                int aoff = u + ((u >> 6) << 3);
                bf16x8 ah = *(const bf16x8*)&s_a[aoff];
                bf16x8 bh = *(const bf16x8*)&WF[(nt << 12) + (ks << 9)];
                acc = __builtin_amdgcn_mfma_f32_16x16x32_bf16(ah, bh, acc, 0, 0, 0);
            }
            #pragma unroll
            for (int j = 0; j < 4; ++j) {
                int f = f0 + rh * 16 + koct * 4 + j;
                if (f < NF) X[((long)bi * NF + f) * 256 + nt * 16 + sel16] = acc[j];
            }
        }
    }
}

/* ---- params (+ acc zeroing) ---- */
__global__ __launch_bounds__(64) void k_params(const float* __restrict__ h_part,
                                               const float* __restrict__ w2,
                                               const float* __restrict__ b1,
                                               const float* __restrict__ b2,
                                               float* __restrict__ par,
                                               float* __restrict__ accz) {
    __shared__ float s_h[CONDC];
    const int f = blockIdx.x;
    const int b = blockIdx.y;
    const int t = threadIdx.x;
    {
        int gid = (b * NF + f) * 64 + t;
        for (int u = gid; u < ACC_N; u += NF * NB * 64) accz[u] = 0.f;
    }
    if (t < CONDC) {
        float v = b1[t];
        #pragma unroll
        for (int g = 0; g < 4; ++g)
            v += h_part[(((long)g * NB + b) * NF + f) * CONDC + t];
        s_h[t] = (v >= 0.f) ? v : 0.01f * v;
    }
    __syncthreads();
    float acc = b2[t];
    #pragma unroll 8
    for (int cin = 0; cin < CONDC; ++cin) acc += s_h[cin] * w2[t * CONDC + cin];
    par[((long)b * NF + f) * 64 + t] = tanhf(acc);
}

/* ---- FUSED (R25-exact champion): H lerp + 1-shfl cmul + 16-row iDFT + OLA +
   fused interior normalization. grid 2080 = 4*520, idx%8==b XCD affinity. ---- */
__global__ __launch_bounds__(256) void k_fused(const float* __restrict__ par,
                                               const unsigned* __restrict__ g2,
                                               const unsigned short* __restrict__ wtab,
                                               const float* __restrict__ X,
                                               float* __restrict__ accb,
                                               const float* __restrict__ bias,
                                               float* __restrict__ out) {
    __shared__ __align__(16) unsigned short s_y[16 * FPAD];   /* 8.4 KB */
    __shared__ float s_ola[1216];                              /* 4.9 KB */
    __shared__ float s_parl[256];                              /* 1 KB */

    const int idx = blockIdx.x;     /* 0..2079 */
    const int o = idx / 520;
    const int rem = idx - o * 520;
    const int ftile = rem >> 3;     /* 0..64 */
    const int b = rem & 7;
    const int bo = b * 4 + o;
    const int t = threadIdx.x;
    const int f0 = ftile * 16;
    const int w = t >> 6;           /* 0..3 */
    const int l = t & 63;
    const int sel16 = l & 15;
    const int koct = l >> 4;

    const unsigned short* WI = wtab + 2 * 65536 + (l << 3);
    const float biaso = bias[o];

    {
        int f_r = t >> 4;
        int idx2 = t & 15;
        int isel = idx2 >> 3;
        int q = idx2 & 7;
        int col = (o * 2 + isel) * 4 + (q & 3) + ((q >> 2) * 32);
        int fc = f0 + f_r;
        if (fc >= NF) fc = NF - 1;
        s_parl[t] = par[((long)b * NF + fc) * 64 + col];
    }
    __syncthreads();

    #pragma unroll 4
    for (int r = 0; r < 16; ++r) {
        int f = f0 + r;
        bool valid = (f < NF);
        float yv = 0.f;
        #pragma unroll
        for (int i = 0; i < 2; ++i) {
            const float* pp = &s_parl[r * 16 + i * 8];
            float H = 0.f;
            #pragma unroll
            for (int s4 = 0; s4 < 4; ++s4) {
                float a = pp[s4];
                float wv = pp[4 + s4];
                float u = (wv + 1.f) * 128.f;
                float fu = floorf(u);
                int gi = (int)fu;
                gi = (gi < 0) ? 0 : (gi > 255 ? 255 : gi);
                float frac = u - (float)gi;
                unsigned pk = g2[(gi << 8) + t];
                float glo = frombf16((unsigned short)(pk & 0xffffu));
                float ghi = frombf16((unsigned short)(pk >> 16));
                H += a * (glo + frac * (ghi - glo));
            }
            float2 xp = make_float2(0.f, 0.f);
            if (valid) xp = *(const float2*)&X[((long)(b * 2 + i) * NF + f) * 256 + (t & ~1)];
            float Hx = __shfl_xor(H, 1);
            float contrib;
            if (t < 2) contrib = H * ((t & 1) ? xp.y : xp.x);
            else contrib = (t & 1) ? (H * xp.x + Hx * xp.y)
                                   : (H * xp.x - Hx * xp.y);
            yv += contrib;
        }
        s_y[r * FPAD + t] = tobf16_rn(yv);
    }

    __syncthreads();
    for (int u = t; u < 1216; u += 256) s_ola[u] = 0.f;
    __syncthreads();
    for (int s = 0; s < 4; ++s) {
        const int nt = w * 4 + s;
        f32x4 acc = {0.f, 0.f, 0.f, 0.f};
        #pragma unroll
        for (int ks = 0; ks < 8; ++ks) {
            bf16x8 ah = *(const bf16x8*)&s_y[sel16 * FPAD + ks * 32 + koct * 8];
            bf16x8 bh = *(const bf16x8*)&WI[(nt << 12) + (ks << 9)];
            acc = __builtin_amdgcn_mfma_f32_16x16x32_bf16(ah, bh, acc, 0, 0, 0);
        }
        #pragma unroll
        for (int j = 0; j < 4; ++j) {
            int row = koct * 4 + j;
            int n = nt * 16 + sel16;
            atomicAdd(&s_ola[row * 64 + n], acc[j]);
        }
    }
    __syncthreads();
    /* epilogue: edges -> atomic acc; interior pos<65536 -> out directly (env=1.5) */
    for (int u = t; u < 1216; u += 256) {
        long pos = (long)f0 * HOP + u;
        if (pos >= (long)LL) continue;
        float v = s_ola[u];
        if (u < 192 || u >= 1024) {
            atomicAdd(&accb[(long)bo * LL + pos], v);
        } else if (pos < 65536) {
            out[(long)bo * TT + (pos - 128)] = v * (1.f / 1.5f) + biaso;
        }
    }
}

/* ---- norm: boundary/overlap samples only (verified R25) ---- */
__global__ __launch_bounds__(256) void k_norm(const float* __restrict__ accbuf,
                                              const float* __restrict__ bias,
                                              float* __restrict__ out) {
    int idx = blockIdx.x * 256 + threadIdx.x;
    if (idx >= NB * OUT_CHN * TT) return;
    int tpos = idx & (TT - 1);
    int bo = idx >> 16;
    int o = bo & 3;
    int tt = tpos + 128;
    if (tt >= 192 && tt < 65536 && (tt & 1023) >= 192) return;
    float env;
    if (tt >= 192 && tt < (NF - 1) * HOP) {
        env = 1.5f;
    } else {
        env = 0.f;
        int fhi = tt >> 6;
        #pragma unroll
        for (int d = 0; d < 4; ++d) {
            int f = fhi - d;
            int n = tt - f * HOP;
            if (f >= 0 && f < NF && n >= 0 && n < KK) {
                float angn = (2.f * PI_F / 256.f) * (float)n;
                float wv = 0.5f * (1.f - cosf(angn));
                env += wv * wv;
            }
        }
    }
    out[idx] = accbuf[(long)bo * LL + tt] / env + bias[o];
}

extern "C" void kernel_launch(void* const* d_in, const int* in_sizes, int n_in,
                              void* d_out, int out_size, void* d_ws, size_t ws_size,
                              hipStream_t stream) {
    const float* x    = (const float*)d_in[0];
    const float* cond = (const float*)d_in[1];
    const float* w1   = (const float*)d_in[2];
    const float* b1   = (const float*)d_in[3];
    const float* w2   = (const float*)d_in[4];
    const float* b2   = (const float*)d_in[5];
    const float* bias = (const float*)d_in[6];
    float* out = (float*)d_out;
    float* ws  = (float*)d_ws;
    unsigned short* wtab = (unsigned short*)(ws + WTAB_OFF);
    float* par    = ws + PAR_OFF;
    float* X      = ws + X_OFF;
    float* acc    = ws + ACC_OFF;
    float* h_part = ws + HPART_OFF;
    unsigned* g2  = (unsigned*)(ws + G2_OFF);
    unsigned short* wfh = (unsigned short*)(ws + WFH_OFF);

    hipLaunchKernelGGL(k_setup, dim3(2049), dim3(256), 0, stream,
                       wtab, w1, wfh, (unsigned short*)g2);
    hipLaunchKernelGGL(k_heavy, dim3(1072), dim3(256), 0, stream,
                       cond, wfh, h_part, x, wtab, X);
    hipLaunchKernelGGL(k_params, dim3(NF, NB), dim3(64), 0, stream, h_part, w2, b1, b2, par, acc);
    hipLaunchKernelGGL(k_fused, dim3(2080), dim3(256), 0, stream, par, g2, wtab, X, acc, bias, out);
    hipLaunchKernelGGL(k_norm, dim3(8192), dim3(256), 0, stream, acc, bias, out);
}